// Round 1
// baseline (285.568 us; speedup 1.0000x reference)
//
#include <hip/hip_runtime.h>
#include <math.h>

#define T_TOK 2048
#define HD 768
#define ID 1536
#define NE 8
#define CAP 768
#define TK 4096
#define MAXTILES 40

typedef __bf16 bf16_t;
typedef __bf16 bf16x8 __attribute__((ext_vector_type(8)));
typedef float floatx4 __attribute__((ext_vector_type(4)));

__device__ __forceinline__ void gld16(const bf16_t* g, bf16_t* l) {
  __builtin_amdgcn_global_load_lds(
      (__attribute__((address_space(1))) void*)(g),
      (__attribute__((address_space(3))) void*)(l),
      16, 0, 0);
}

// ---------------- K0: x fp32 -> bf16, zero importance ----------------
__global__ void k_cvt_x(const float* __restrict__ x, bf16_t* __restrict__ xbf,
                        float* __restrict__ imp) {
  int i = blockIdx.x * 256 + threadIdx.x;           // 196608 threads, 8 elem each
  if (blockIdx.x == 0 && threadIdx.x < NE) imp[threadIdx.x] = 0.f;
  const float4* xs = (const float4*)x;
  float4 a = xs[i * 2], b = xs[i * 2 + 1];
  bf16x8 v;
  v[0] = (bf16_t)a.x; v[1] = (bf16_t)a.y; v[2] = (bf16_t)a.z; v[3] = (bf16_t)a.w;
  v[4] = (bf16_t)b.x; v[5] = (bf16_t)b.y; v[6] = (bf16_t)b.z; v[7] = (bf16_t)b.w;
  *(bf16x8*)(xbf + (size_t)i * 8) = v;
}

// ---------------- K1: routing (one wave per token) ----------------
__global__ void k_route(const float* __restrict__ x, const float* __restrict__ wg,
                        int2* __restrict__ idx2, float2* __restrict__ wc2,
                        float* __restrict__ imp) {
  int t = blockIdx.x;
  int lane = threadIdx.x;      // 64
  const float* xr = x + (size_t)t * HD;
  float acc[8] = {0, 0, 0, 0, 0, 0, 0, 0};
  for (int j = 0; j < 12; ++j) {
    int h = j * 64 + lane;
    float xv = xr[h];
    const float4* wr = (const float4*)(wg + (size_t)h * 8);
    float4 w0 = wr[0], w1 = wr[1];
    acc[0] += xv * w0.x; acc[1] += xv * w0.y; acc[2] += xv * w0.z; acc[3] += xv * w0.w;
    acc[4] += xv * w1.x; acc[5] += xv * w1.y; acc[6] += xv * w1.z; acc[7] += xv * w1.w;
  }
#pragma unroll
  for (int e = 0; e < 8; ++e) {
    float v = acc[e];
    for (int s = 1; s < 64; s <<= 1) v += __shfl_xor(v, s, 64);
    acc[e] = v;
  }
  // softmax (all lanes redundantly; values identical)
  float mx = acc[0];
#pragma unroll
  for (int e = 1; e < 8; ++e) mx = fmaxf(mx, acc[e]);
  float p[8], sum = 0.f;
#pragma unroll
  for (int e = 0; e < 8; ++e) { p[e] = __expf(acc[e] - mx); sum += p[e]; }
#pragma unroll
  for (int e = 0; e < 8; ++e) p[e] /= sum;
  if (lane < 8) atomicAdd(&imp[lane], p[lane]);
  if (lane == 0) {
    int e0 = 0;
#pragma unroll
    for (int e = 1; e < 8; ++e) if (p[e] > p[e0]) e0 = e;
    int e1 = (e0 == 0) ? 1 : 0;
#pragma unroll
    for (int e = 0; e < 8; ++e) if (e != e0 && p[e] > p[e1]) e1 = e;
    float denom = p[e0] + p[e1] + 1e-8f;
    float w0c = fminf(fmaxf(p[e0] / denom, 1e-8f), 10.f);
    float w1c = fminf(fmaxf(p[e1] / denom, 1e-8f), 10.f);
    idx2[t] = make_int2(e0, e1);
    wc2[t] = make_float2(w0c, w1c);
  }
}

// ---------------- K2: capacity scan + list build + aux ----------------
__global__ void k_scan(const int2* __restrict__ idx2, const float2* __restrict__ wc2,
                       const float* __restrict__ imp,
                       int* __restrict__ tok_of_row, float* __restrict__ wgt_of_row,
                       int2* __restrict__ tok_rows, int4* __restrict__ tiles,
                       int* __restrict__ meta, float* __restrict__ aux_out) {
  __shared__ int sA[256][16];
  __shared__ int sB[256][8];
  __shared__ int tot8[8];
  int tid = threadIdx.x;
  int t0 = tid * 8;
#pragma unroll
  for (int c = 0; c < 16; ++c) sA[tid][c] = 0;
#pragma unroll
  for (int c = 0; c < 8; ++c) sB[tid][c] = 0;
  for (int j = 0; j < 8; ++j) {
    int t = t0 + j;
    int2 e2 = idx2[t];
    sA[tid][e2.x]++;
    sA[tid][8 + e2.y]++;
    tok_rows[t] = make_int2(-1, -1);
  }
  __syncthreads();
  // inclusive scan over threads, 16 cols
  for (int s = 1; s < 256; s <<= 1) {
    int v[16];
    if (tid >= s) {
#pragma unroll
      for (int c = 0; c < 16; ++c) v[c] = sA[tid - s][c];
    }
    __syncthreads();
    if (tid >= s) {
#pragma unroll
      for (int c = 0; c < 16; ++c) sA[tid][c] += v[c];
    }
    __syncthreads();
  }
  {  // convert to exclusive
    int v[16];
#pragma unroll
    for (int c = 0; c < 16; ++c) v[c] = (tid > 0) ? sA[tid - 1][c] : 0;
    __syncthreads();
#pragma unroll
    for (int c = 0; c < 16; ++c) sA[tid][c] = v[c];
    __syncthreads();
  }
  // walk 1: ranks + keep mask + kept-per-expert counts
  int keepmask = 0;
  for (int j = 0; j < 8; ++j) {
    int t = t0 + j;
    int2 e2 = idx2[t];
    int r0 = ++sA[tid][e2.x];
    if (r0 <= CAP) { keepmask |= 1 << (j * 2); sB[tid][e2.x]++; }
    int r1 = ++sA[tid][8 + e2.y];
    if (r1 <= CAP) { keepmask |= 1 << (j * 2 + 1); sB[tid][e2.y]++; }
  }
  __syncthreads();
  for (int s = 1; s < 256; s <<= 1) {
    int v[8];
    if (tid >= s) {
#pragma unroll
      for (int c = 0; c < 8; ++c) v[c] = sB[tid - s][c];
    }
    __syncthreads();
    if (tid >= s) {
#pragma unroll
      for (int c = 0; c < 8; ++c) sB[tid][c] += v[c];
    }
    __syncthreads();
  }
  if (tid == 255) {
#pragma unroll
    for (int c = 0; c < 8; ++c) tot8[c] = sB[255][c];
  }
  __syncthreads();
  {
    int v[8];
#pragma unroll
    for (int c = 0; c < 8; ++c) v[c] = (tid > 0) ? sB[tid - 1][c] : 0;
    __syncthreads();
#pragma unroll
    for (int c = 0; c < 8; ++c) sB[tid][c] = v[c];
    __syncthreads();
  }
  int start8[8];
  {
    int run = 0;
#pragma unroll
    for (int c = 0; c < 8; ++c) { start8[c] = run; run += tot8[c]; }
  }
  // walk 2: placement
  for (int j = 0; j < 8; ++j) {
    int t = t0 + j;
    int2 e2 = idx2[t];
    float2 wv = wc2[t];
    if (keepmask & (1 << (j * 2))) {
      int pos = sB[tid][e2.x]++;
      int grow = start8[e2.x] + pos;
      tok_of_row[grow] = t; wgt_of_row[grow] = wv.x;
      tok_rows[t].x = grow;
    }
    if (keepmask & (1 << (j * 2 + 1))) {
      int pos = sB[tid][e2.y]++;
      int grow = start8[e2.y] + pos;
      tok_of_row[grow] = t; wgt_of_row[grow] = wv.y;
      tok_rows[t].y = grow;
    }
  }
  __syncthreads();
  if (tid == 0) {
    int numt = 0, totk = 0;
    for (int e = 0; e < NE; ++e) {
      int n = tot8[e]; totk += n; int s = start8[e];
      for (int j = 0; j < n; j += 128) tiles[numt++] = make_int4(e, s + j, min(128, n - j), 0);
    }
    meta[0] = numt;
    int dropped = TK - totk;
    float a = 0.f;
    for (int e = 0; e < NE; ++e)
      a += ((float)tot8[e] / (float)TK) * (imp[e] / (float)T_TOK);
    a *= (float)NE;
    if (dropped > 0) a += (float)dropped / (float)T_TOK * 0.1f;
    a = fminf(a, 1.f) * 0.001f;
    aux_out[0] = a;
  }
}

// ---------------- K3: fp32 [E][R][C] -> bf16 [E][C][R] transpose ----------------
__global__ void k_tr(const float* __restrict__ src, bf16_t* __restrict__ dst,
                     int R, int C) {
  __shared__ bf16_t tl[64][65];
  int e = blockIdx.z;
  int r0 = blockIdx.y * 64, c0 = blockIdx.x * 64;
  int tid = threadIdx.x;
  int lr = tid >> 2, lc = (tid & 3) * 16;
  const float* s = src + ((size_t)e * R + (r0 + lr)) * C + c0 + lc;
#pragma unroll
  for (int j = 0; j < 16; j += 4) {
    float4 v = *(const float4*)(s + j);
    tl[lr][lc + j + 0] = (bf16_t)v.x;
    tl[lr][lc + j + 1] = (bf16_t)v.y;
    tl[lr][lc + j + 2] = (bf16_t)v.z;
    tl[lr][lc + j + 3] = (bf16_t)v.w;
  }
  __syncthreads();
  int oc = tid >> 2, orr = (tid & 3) * 16;
  bf16_t* d = dst + ((size_t)e * C + (c0 + oc)) * R + r0 + orr;
  bf16x8 v0, v1;
#pragma unroll
  for (int j = 0; j < 8; ++j) v0[j] = tl[orr + j][oc];
#pragma unroll
  for (int j = 0; j < 8; ++j) v1[j] = tl[orr + 8 + j][oc];
  *(bf16x8*)d = v0;
  *(bf16x8*)(d + 8) = v1;
}

// ---------------- K4: grouped GEMM1 (g,u) + SiLU -> h (bf16) ----------------
__global__ __launch_bounds__(256, 2)
void k_gemm1(const bf16_t* __restrict__ xbf, const bf16_t* __restrict__ w1t,
             const bf16_t* __restrict__ w3t, const int* __restrict__ tok_of_row,
             const int4* __restrict__ tiles, const int* __restrict__ meta,
             bf16_t* __restrict__ h_ws) {
  int numt = meta[0];
  int bx = blockIdx.x;
  if (bx >= numt) return;
  int4 tlr = tiles[bx];
  int e = tlr.x, grow0 = tlr.y, nrows = tlr.z;
  int cy = blockIdx.y;  // 0..11

  __shared__ __attribute__((aligned(16))) bf16_t Abuf[128 * 32];
  __shared__ __attribute__((aligned(16))) bf16_t B1buf[128 * 32];
  __shared__ __attribute__((aligned(16))) bf16_t B3buf[128 * 32];

  int tid = threadIdx.x;
  int lane = tid & 63, wv = tid >> 6;
  int wm = wv & 1, wn = wv >> 1;
  int lr = lane & 15, q = lane >> 4;
  int rdc = (q ^ ((lane >> 1) & 3)) * 8;           // swizzled read chunk
  int srow = lane >> 2;
  int gch = ((lane & 3) ^ ((lane >> 3) & 3)) * 8;  // swizzled global source chunk

  int ra = wv * 32 + srow;
  int tokA0 = tok_of_row[grow0 + min(ra, nrows - 1)];
  int tokA1 = tok_of_row[grow0 + min(ra + 16, nrows - 1)];
  const bf16_t* gA0 = xbf + (size_t)tokA0 * HD + gch;
  const bf16_t* gA1 = xbf + (size_t)tokA1 * HD + gch;
  int nb = cy * 128 + wv * 32 + srow;
  const bf16_t* gB1a = w1t + ((size_t)e * ID + nb) * HD + gch;
  const bf16_t* gB1b = gB1a + (size_t)16 * HD;
  const bf16_t* gB3a = w3t + ((size_t)e * ID + nb) * HD + gch;
  const bf16_t* gB3b = gB3a + (size_t)16 * HD;
  bf16_t* lA0 = &Abuf[(wv * 32) * 32];
  bf16_t* lA1 = &Abuf[(wv * 32 + 16) * 32];
  bf16_t* lB1a = &B1buf[(wv * 32) * 32];
  bf16_t* lB1b = &B1buf[(wv * 32 + 16) * 32];
  bf16_t* lB3a = &B3buf[(wv * 32) * 32];
  bf16_t* lB3b = &B3buf[(wv * 32 + 16) * 32];

  floatx4 accg[4][4] = {};
  floatx4 accu[4][4] = {};

  for (int kk = 0; kk < 24; ++kk) {
    __syncthreads();
    gld16(gA0, lA0);  gld16(gA1, lA1);
    gld16(gB1a, lB1a); gld16(gB1b, lB1b);
    gld16(gB3a, lB3a); gld16(gB3b, lB3b);
    gA0 += 32; gA1 += 32; gB1a += 32; gB1b += 32; gB3a += 32; gB3b += 32;
    __syncthreads();
    bf16x8 af[4], b1f[4], b3f[4];
#pragma unroll
    for (int i = 0; i < 4; ++i) af[i] = *(const bf16x8*)&Abuf[(wm * 64 + i * 16 + lr) * 32 + rdc];
#pragma unroll
    for (int i = 0; i < 4; ++i) b1f[i] = *(const bf16x8*)&B1buf[(wn * 64 + i * 16 + lr) * 32 + rdc];
#pragma unroll
    for (int i = 0; i < 4; ++i) b3f[i] = *(const bf16x8*)&B3buf[(wn * 64 + i * 16 + lr) * 32 + rdc];
#pragma unroll
    for (int i = 0; i < 4; ++i)
#pragma unroll
      for (int j = 0; j < 4; ++j) {
        accg[i][j] = __builtin_amdgcn_mfma_f32_16x16x32_bf16(af[i], b1f[j], accg[i][j], 0, 0, 0);
        accu[i][j] = __builtin_amdgcn_mfma_f32_16x16x32_bf16(af[i], b3f[j], accu[i][j], 0, 0, 0);
      }
  }
#pragma unroll
  for (int i = 0; i < 4; ++i)
#pragma unroll
    for (int r = 0; r < 4; ++r) {
      int rl = wm * 64 + i * 16 + q * 4 + r;
      if (rl < nrows) {
        size_t rb = (size_t)(grow0 + rl) * ID + cy * 128 + wn * 64 + lr;
#pragma unroll
        for (int j = 0; j < 4; ++j) {
          float gg = accg[i][j][r], uu = accu[i][j][r];
          float sg = gg / (1.f + __expf(-gg));
          h_ws[rb + j * 16] = (bf16_t)(sg * uu);
        }
      }
    }
}

// ---------------- K5: grouped GEMM2 y = h @ w2^T ----------------
__global__ __launch_bounds__(256, 2)
void k_gemm2(const bf16_t* __restrict__ h_ws, const bf16_t* __restrict__ w2t,
             const int4* __restrict__ tiles, const int* __restrict__ meta,
             float* __restrict__ y_ws) {
  int numt = meta[0];
  int bx = blockIdx.x;
  if (bx >= numt) return;
  int4 tlr = tiles[bx];
  int e = tlr.x, grow0 = tlr.y, nrows = tlr.z;
  int cy = blockIdx.y;  // 0..5

  __shared__ __attribute__((aligned(16))) bf16_t Abuf[128 * 32];
  __shared__ __attribute__((aligned(16))) bf16_t Bbuf[128 * 32];

  int tid = threadIdx.x;
  int lane = tid & 63, wv = tid >> 6;
  int wm = wv & 1, wn = wv >> 1;
  int lr = lane & 15, q = lane >> 4;
  int rdc = (q ^ ((lane >> 1) & 3)) * 8;
  int srow = lane >> 2;
  int gch = ((lane & 3) ^ ((lane >> 3) & 3)) * 8;

  int ra = wv * 32 + srow;
  const bf16_t* gA0 = h_ws + (size_t)(grow0 + min(ra, nrows - 1)) * ID + gch;
  const bf16_t* gA1 = h_ws + (size_t)(grow0 + min(ra + 16, nrows - 1)) * ID + gch;
  int nb = cy * 128 + wv * 32 + srow;
  const bf16_t* gB0 = w2t + ((size_t)e * HD + nb) * ID + gch;
  const bf16_t* gB1 = gB0 + (size_t)16 * ID;
  bf16_t* lA0 = &Abuf[(wv * 32) * 32];
  bf16_t* lA1 = &Abuf[(wv * 32 + 16) * 32];
  bf16_t* lB0 = &Bbuf[(wv * 32) * 32];
  bf16_t* lB1 = &Bbuf[(wv * 32 + 16) * 32];

  floatx4 acc[4][4] = {};

  for (int kk = 0; kk < 48; ++kk) {
    __syncthreads();
    gld16(gA0, lA0); gld16(gA1, lA1);
    gld16(gB0, lB0); gld16(gB1, lB1);
    gA0 += 32; gA1 += 32; gB0 += 32; gB1 += 32;
    __syncthreads();
    bf16x8 af[4], bfr[4];
#pragma unroll
    for (int i = 0; i < 4; ++i) af[i] = *(const bf16x8*)&Abuf[(wm * 64 + i * 16 + lr) * 32 + rdc];
#pragma unroll
    for (int i = 0; i < 4; ++i) bfr[i] = *(const bf16x8*)&Bbuf[(wn * 64 + i * 16 + lr) * 32 + rdc];
#pragma unroll
    for (int i = 0; i < 4; ++i)
#pragma unroll
      for (int j = 0; j < 4; ++j)
        acc[i][j] = __builtin_amdgcn_mfma_f32_16x16x32_bf16(af[i], bfr[j], acc[i][j], 0, 0, 0);
  }
#pragma unroll
  for (int i = 0; i < 4; ++i)
#pragma unroll
    for (int r = 0; r < 4; ++r) {
      int rl = wm * 64 + i * 16 + q * 4 + r;
      if (rl < nrows) {
        size_t rb = (size_t)(grow0 + rl) * HD + cy * 128 + wn * 64 + lr;
#pragma unroll
        for (int j = 0; j < 4; ++j) y_ws[rb + j * 16] = acc[i][j][r];
      }
    }
}

// ---------------- K6: combine y rows into out ----------------
__global__ void k_comb(const float* __restrict__ y_ws, const int2* __restrict__ tok_rows,
                       const float* __restrict__ wgt_of_row, float* __restrict__ out) {
  int idx = blockIdx.x * 256 + threadIdx.x;  // 0..393215
  int t = idx / 192;
  int c = idx - t * 192;
  int2 rr = tok_rows[t];
  float vx = 0.f, vy = 0.f, vz = 0.f, vw = 0.f;
  if (rr.x >= 0) {
    float w = wgt_of_row[rr.x];
    float4 a = *(const float4*)(y_ws + (size_t)rr.x * HD + c * 4);
    vx += w * a.x; vy += w * a.y; vz += w * a.z; vw += w * a.w;
  }
  if (rr.y >= 0) {
    float w = wgt_of_row[rr.y];
    float4 a = *(const float4*)(y_ws + (size_t)rr.y * HD + c * 4);
    vx += w * a.x; vy += w * a.y; vz += w * a.z; vw += w * a.w;
  }
  float4 v = make_float4(vx, vy, vz, vw);
  *(float4*)(out + (size_t)t * HD + c * 4) = v;
}

extern "C" void kernel_launch(void* const* d_in, const int* in_sizes, int n_in,
                              void* d_out, int out_size, void* d_ws, size_t ws_size,
                              hipStream_t stream) {
  const float* x  = (const float*)d_in[0];
  const float* wg = (const float*)d_in[1];
  const float* w1 = (const float*)d_in[2];
  const float* w3 = (const float*)d_in[3];
  const float* w2 = (const float*)d_in[4];
  float* out = (float*)d_out;

  char* ws = (char*)d_ws;
  bf16_t* xbf  = (bf16_t*)(ws + 0);          //  3,145,728
  bf16_t* w1t  = (bf16_t*)(ws + 3145728);    // 18,874,368
  bf16_t* w3t  = (bf16_t*)(ws + 22020096);   // 18,874,368
  bf16_t* w2t  = (bf16_t*)(ws + 40894464);   // 18,874,368
  bf16_t* h_ws = (bf16_t*)(ws + 59768832);   // 12,582,912
  float*  y_ws = (float*)(ws + 72351744);    // 12,582,912
  int2*   idx2 = (int2*)(ws + 84934656);
  float2* wc2  = (float2*)(ws + 84951040);
  int*    tok_of_row = (int*)(ws + 84967424);
  float*  wgt_of_row = (float*)(ws + 84983808);
  int2*   tok_rows   = (int2*)(ws + 85000192);
  int4*   tiles      = (int4*)(ws + 85016576);
  int*    meta       = (int*)(ws + 85017600);
  float*  imp        = (float*)(ws + 85017856);

  float* aux_out = out + (size_t)T_TOK * HD;

  k_cvt_x<<<768, 256, 0, stream>>>(x, xbf, imp);
  k_route<<<T_TOK, 64, 0, stream>>>(x, wg, idx2, wc2, imp);
  k_scan<<<1, 256, 0, stream>>>(idx2, wc2, imp, tok_of_row, wgt_of_row,
                                tok_rows, tiles, meta, aux_out);
  k_tr<<<dim3(24, 12, 8), 256, 0, stream>>>(w1, w1t, HD, ID);
  k_tr<<<dim3(24, 12, 8), 256, 0, stream>>>(w3, w3t, HD, ID);
  k_tr<<<dim3(12, 24, 8), 256, 0, stream>>>(w2, w2t, ID, HD);
  k_gemm1<<<dim3(MAXTILES, 12), 256, 0, stream>>>(xbf, w1t, w3t, tok_of_row,
                                                  tiles, meta, h_ws);
  k_gemm2<<<dim3(MAXTILES, 6), 256, 0, stream>>>(h_ws, w2t, tiles, meta, y_ws);
  k_comb<<<1536, 256, 0, stream>>>(y_ws, tok_rows, wgt_of_row, out);
}